// Round 8
// baseline (357.758 us; speedup 1.0000x reference)
//
#include <hip/hip_runtime.h>
#include <hip/hip_bf16.h>

// GQA + RoPE fused block for MI355X (gfx950).
// B=2, T=2048, D=2048, H=32, HKV=8, DH=64, G=4.
// bf16 MFMA 16x16x32 for QKV proj, attention, out proj. fp32 softmax/RoPE.
// Flash v12 = v10's staging (conflict-free gld_lds, swizzled producers,
// permuted V, P-in-registers) + 128-row SINGLE Q-tiles, 4 waves x 32 rows:
// every K/V fragment read feeds 2 MFMAs (both row-groups). Grid (16,H,B) =
// 1024 blocks -> 4 blocks/CU preserved. Causal triangle is inter-block
// variance (nkv = 2qt+2), absorbed by backfill + long-blocks-first order.
// r7 lesson: v11's wave-split halves broke the pairing balance (B-waves
// carried 2x nkvB on a barrier-synced loop -> 1.5x regression). Reuse must
// keep EVERY wave active EVERY iteration. r6 lesson (corrected): v10 LDS
// floor ~43.5us of 68.8; halving reads -> ~22us floor.
// r3: never pin min-waves. r4: no pointer-param lambdas. r5: merged-halves
// per-wave closed (regpressure).

typedef __bf16 bf16_t;
typedef __bf16 bf16x4 __attribute__((ext_vector_type(4)));
typedef __bf16 bf16x8 __attribute__((ext_vector_type(8)));
typedef float f32x4 __attribute__((ext_vector_type(4)));

#define B_ 2
#define T_ 2048
#define D_ 2048
#define H_ 32
#define HKV_ 8
#define DH_ 64

// 2^x via v_exp_f32 (avoid glibc __exp2f macro clash)
__device__ __forceinline__ float fast_exp2(float x) { return __builtin_amdgcn_exp2f(x); }

// async global->LDS, 16B per lane. LDS dest must be wave-uniform base; lane i
// deposits at base + 16*i (no padding allowed in the staged region).
__device__ __forceinline__ void gld_lds16(const bf16_t* g, bf16_t* l) {
  __builtin_amdgcn_global_load_lds((const __attribute__((address_space(1))) unsigned int*)g,
                                   (__attribute__((address_space(3))) unsigned int*)l, 16, 0, 0);
}

// ---------------------------------------------------------------- cast x -> bf16
__global__ __launch_bounds__(256) void cast_f32_bf16(const float* __restrict__ in,
                                                     bf16_t* __restrict__ out, int n) {
  int i = (blockIdx.x * 256 + threadIdx.x) * 8;
  if (i < n) {
    f32x4 a = *(const f32x4*)&in[i];
    f32x4 b = *(const f32x4*)&in[i + 4];
    bf16x8 o;
    o[0] = (bf16_t)a[0]; o[1] = (bf16_t)a[1]; o[2] = (bf16_t)a[2]; o[3] = (bf16_t)a[3];
    o[4] = (bf16_t)b[0]; o[5] = (bf16_t)b[1]; o[6] = (bf16_t)b[2]; o[7] = (bf16_t)b[3];
    *(bf16x8*)&out[i] = o;
  }
}

// ------------------------------------------- transpose + cast: W[K][N] -> Wt[N][K]
__global__ __launch_bounds__(256) void transpose_w(const float* __restrict__ W,
                                                   bf16_t* __restrict__ Wt, int K, int N) {
  __shared__ float tile[64][65];
  int n0 = blockIdx.x * 64, k0 = blockIdx.y * 64;
  int tid = threadIdx.x;
  for (int i = tid; i < 4096; i += 256) {
    int r = i >> 6, c = i & 63;
    tile[r][c] = W[(size_t)(k0 + r) * N + n0 + c];
  }
  __syncthreads();
  for (int i = tid; i < 4096; i += 256) {
    int r = i >> 6, c = i & 63;
    Wt[(size_t)(n0 + r) * K + k0 + c] = (bf16_t)tile[c][r];
  }
}

// --------------------- fused transpose+cast of Wq|Wk|Wv into wqkvb[3072][2048]
__global__ __launch_bounds__(256) void transpose_wqkv(const float* __restrict__ Wq,
                                                      const float* __restrict__ Wk,
                                                      const float* __restrict__ Wv,
                                                      bf16_t* __restrict__ Wt) {
  __shared__ float tile[64][65];
  int n0 = blockIdx.x * 64, k0 = blockIdx.y * 64;
  const float* W;
  int srcN, col;
  if (n0 < 2048) { W = Wq; srcN = 2048; col = n0; }
  else if (n0 < 2560) { W = Wk; srcN = 512; col = n0 - 2048; }
  else { W = Wv; srcN = 512; col = n0 - 2560; }
  int tid = threadIdx.x;
  for (int i = tid; i < 4096; i += 256) {
    int r = i >> 6, c = i & 63;
    tile[r][c] = W[(size_t)(k0 + r) * srcN + col + c];
  }
  __syncthreads();
  for (int i = tid; i < 4096; i += 256) {
    int r = i >> 6, c = i & 63;
    Wt[(size_t)(n0 + r) * 2048 + k0 + c] = (bf16_t)tile[c][r];
  }
}

// ---------------------------------------------------------------- bf16 MFMA GEMM
// m97 structure, BK=64 as two concatenated stride-32 sub-blocks: keeps the
// bank-optimal 32-elem row stride and gld_lds16 lane order; halves barriers.
template <typename OutT>
__global__ __launch_bounds__(256) void gemm_bt(const bf16_t* __restrict__ A,
                                               const bf16_t* __restrict__ Bt,
                                               OutT* __restrict__ C, int M, int N, int K) {
  __shared__ __align__(16) bf16_t As[2 * 128 * 32];
  __shared__ __align__(16) bf16_t Bs[2 * 128 * 32];
  int tid = threadIdx.x;
  int lane = tid & 63;
  int wave = tid >> 6;
  int l15 = lane & 15;
  int quad = lane >> 4;
  int m0 = blockIdx.y * 128;
  int n0 = blockIdx.x * 128;
  int wrow = (wave >> 1) * 64;
  int wcol = (wave & 1) * 64;

  f32x4 acc[4][4] = {};

  for (int kc = 0; kc < K; kc += 64) {
#pragma unroll
    for (int kk = 0; kk < 2; ++kk) {
#pragma unroll
      for (int c = 0; c < 2; ++c) {
        int linear = c * 256 + tid;
        int r = linear >> 2, seg = linear & 3;
        gld_lds16(&A[(size_t)(m0 + r) * K + kc + kk * 32 + seg * 8],
                  &As[kk * 4096 + (size_t)(c * 256 + wave * 64) * 8]);
        gld_lds16(&Bt[(size_t)(n0 + r) * K + kc + kk * 32 + seg * 8],
                  &Bs[kk * 4096 + (size_t)(c * 256 + wave * 64) * 8]);
      }
    }
    __syncthreads();
#pragma unroll
    for (int kk = 0; kk < 2; ++kk) {
      bf16x8 af[4], bfr[4];
#pragma unroll
      for (int mi = 0; mi < 4; ++mi)
        af[mi] = *(const bf16x8*)&As[kk * 4096 + (wrow + mi * 16 + l15) * 32 + quad * 8];
#pragma unroll
      for (int ni = 0; ni < 4; ++ni)
        bfr[ni] = *(const bf16x8*)&Bs[kk * 4096 + (wcol + ni * 16 + l15) * 32 + quad * 8];
#pragma unroll
      for (int mi = 0; mi < 4; ++mi)
#pragma unroll
        for (int ni = 0; ni < 4; ++ni)
          acc[mi][ni] = __builtin_amdgcn_mfma_f32_16x16x32_bf16(af[mi], bfr[ni], acc[mi][ni], 0, 0, 0);
    }
    __syncthreads();
  }
#pragma unroll
  for (int mi = 0; mi < 4; ++mi) {
#pragma unroll
    for (int ni = 0; ni < 4; ++ni) {
#pragma unroll
      for (int r = 0; r < 4; ++r) {
        int m = m0 + wrow + mi * 16 + quad * 4 + r;
        int n = n0 + wcol + ni * 16 + l15;
        C[(size_t)m * N + n] = (OutT)acc[mi][ni][r];
      }
    }
  }
}

// ------------------------------------------------- RoPE on q,k + head-major relayout
// qkv rows (bf16): [q 2048 | k 512 | v 512]. qr: [B][H][T][DH], kr: [B][HKV][T][DH].
// Q is pre-scaled by log2(e)/sqrt(64) so flash's softmax is bare exp2(q.k).
// K rows are stored SLOT-SWIZZLED (elem j -> j ^ ((t&7)<<3), 16B granules) so
// flash's linear gld_lds16 deposit lands in the bank-conflict-free layout.
__global__ __launch_bounds__(256) void rope_qk(const bf16_t* __restrict__ qkv,
                                               bf16_t* __restrict__ qr,
                                               bf16_t* __restrict__ kr) {
  int t = blockIdx.x, b = blockIdx.y;
  int tid = threadIdx.x;
  const bf16_t* row = qkv + (size_t)(b * T_ + t) * 3072;
  const float LN1E4_over32 = 9.210340371976184f / 32.0f;
  const float QSC = 1.44269504088896f * 0.125f;  // log2(e)/sqrt(64)
  int ksw = (t & 7) << 3;
  for (int i = tid; i < 1024 + 256; i += 256) {
    bool isq = i < 1024;
    int ii = isq ? i : i - 1024;
    int hh = ii >> 5, j = ii & 31;
    int base = isq ? 0 : 2048;
    float inv = __expf(-(float)j * LN1E4_over32);
    float fr = (float)t * inv;
    float sn, cs;
    sincosf(fr, &sn, &cs);
    float x1 = (float)row[base + hh * 64 + j];
    float x2 = (float)row[base + hh * 64 + j + 32];
    float o1 = x1 * cs - x2 * sn;
    float o2 = x2 * cs + x1 * sn;
    if (isq) {
      size_t o = ((size_t)(b * H_ + hh) * T_ + t) * DH_;
      qr[o + j] = (bf16_t)(o1 * QSC);
      qr[o + j + 32] = (bf16_t)(o2 * QSC);
    } else {
      size_t o = ((size_t)(b * HKV_ + hh) * T_ + t) * DH_;
      kr[o + (j ^ ksw)] = (bf16_t)o1;
      kr[o + ((j + 32) ^ ksw)] = (bf16_t)o2;
    }
  }
}

// ----------------------------------------- V: transpose to [B][HKV][DH][T] (bf16)
// Two layered transforms on the kv-column index within each 64-wide tile:
// (1) PERMUTE f(n) = 32*b5 + 16*b2 + 4*(b4b3) + (b1b0) so flash's PV A-fragment
//     (P values) is lane-local after the swapped QK^T (see v6 notes);
// (2) SLOT-SWIZZLE col ^= (dd&7)<<3 (16B granules) so flash's linear gld_lds16
//     deposit of each 128B row lands bank-conflict-free for the swizzled reads.
__global__ __launch_bounds__(256) void transpose_v(const bf16_t* __restrict__ qkv,
                                                   bf16_t* __restrict__ vtr) {
  __shared__ __align__(16) bf16_t tile[64][72];
  int t0 = blockIdx.x * 64;
  int hk = blockIdx.y;
  int b = blockIdx.z;
  int tid = threadIdx.x;
  for (int i = tid; i < 512; i += 256) {
    int r = i >> 3, s = i & 7;
    *(bf16x8*)&tile[r][s * 8] =
        *(const bf16x8*)&qkv[(size_t)(b * T_ + t0 + r) * 3072 + 2560 + hk * 64 + s * 8];
  }
  __syncthreads();
  for (int i = tid; i < 4096; i += 256) {
    int dd = i >> 6, tt = i & 63;
    int src = (tt & 32) | ((tt & 4) << 2) | ((tt & 24) >> 1) | (tt & 3);
    int dst = tt ^ ((dd & 7) << 3);
    vtr[((size_t)(b * HKV_ + hk) * DH_ + dd) * T_ + t0 + dst] = tile[src][dd];
  }
}

// ---------------------------------------------------------------- flash attention v12
// grid (16 qtiles, H, B) = 1024 blocks, 256 threads (4 waves). Block handles ONE
// 128-row Q-tile (qt = 15 - blockIdx.x: long blocks dispatched first). Wave owns
// 32 q-rows as two 16-row fragments -> each K/V LDS fragment read feeds TWO
// MFMAs; ALL waves active every iteration (r7 lesson). nkv = 2qt+2 varies per
// block; backfill absorbs the triangle. Fully-masked wave-iterations skipped
// wave-uniformly (exp2(-1e30)=0 makes skip exact).
// Staging via global_load_lds: linear LDS dest, pre-swizzled global sources;
// one barrier per kv tile (implicit vmcnt(0) drain orders deposits & frees the
// previous buffer). 32 KB LDS.
__global__ __launch_bounds__(256) void flash_attn(const bf16_t* __restrict__ qr,
                                                  const bf16_t* __restrict__ kr,
                                                  const bf16_t* __restrict__ vtr,
                                                  bf16_t* __restrict__ ctxb) {
  __shared__ __align__(16) bf16_t Ks[2][64 * 64];
  __shared__ __align__(16) bf16_t Vt[2][64 * 64];
  int tid = threadIdx.x;
  int lane = tid & 63;
  int wave = tid >> 6;
  int l15 = lane & 15, quad = lane >> 4;
  int swz = (l15 & 7) * 8;
  int qt = 15 - blockIdx.x, h = blockIdx.y, b = blockIdx.z;
  int nkv = 2 * qt + 2;
  int kvh = h >> 2;
  int wrow = wave * 32;  // wave's first row within the 128-row tile
  int row0 = qt * 128 + wrow;

  const bf16_t* qb = qr + ((size_t)(b * H_ + h) * T_ + row0) * DH_;
  const bf16_t* kbase = kr + (size_t)(b * HKV_ + kvh) * T_ * DH_;
  const bf16_t* vbase = vtr + (size_t)(b * HKV_ + kvh) * DH_ * T_;

  // Q fragments (B-operand layout: lane l15 = qrow-in-frag, k = quad*8+j)
  bf16x8 q[2][2];
#pragma unroll
  for (int rg = 0; rg < 2; ++rg)
#pragma unroll
    for (int k0 = 0; k0 < 2; ++k0)
      q[rg][k0] = *(const bf16x8*)&qb[(rg * 16 + l15) * 64 + k0 * 32 + quad * 8];

  f32x4 o[2][4] = {};
  float l0 = 0.f, l1 = 0.f;

  // async stage of one K/V tile (8 KB each) into buffer bf: 4 gld_lds16/thread.
  auto stage = [&](int kv, int bf) {
#pragma unroll
    for (int c = 0; c < 2; ++c) {
      int idx = c * 256 + tid;
      bf16_t* dst = &Ks[bf][(c * 256 + wave * 64) * 8];
      gld_lds16(&kbase[(size_t)kv * 4096 + idx * 8], dst);
      bf16_t* dstv = &Vt[bf][(c * 256 + wave * 64) * 8];
      gld_lds16(&vbase[(size_t)(idx >> 3) * T_ + kv * 64 + (idx & 7) * 8], dstv);
    }
  };
  stage(0, 0);

  for (int kv = 0; kv < nkv; ++kv) {
    const bf16_t* ks = Ks[kv & 1];
    const bf16_t* vt = Vt[kv & 1];
    // barrier drains vmcnt -> deposits for tile kv landed (all waves), and all
    // waves finished compute(kv-1) -> buf^1 is free for the next prefetch.
    __syncthreads();
    if (kv + 1 < nkv) stage(kv + 1, (kv + 1) & 1);

    // skip wave-iterations where every element is causally masked (wave-uniform)
    if (kv * 64 <= row0 + 31) {
      // ---- QK^T: each K fragment read once, feeds both row-groups
      f32x4 s[2][4] = {};
#pragma unroll
      for (int mt = 0; mt < 4; ++mt) {
        bf16x8 ak0 = *(const bf16x8*)&ks[(mt * 16 + l15) * 64 + ((quad * 8) ^ swz)];
        bf16x8 ak1 = *(const bf16x8*)&ks[(mt * 16 + l15) * 64 + ((32 + quad * 8) ^ swz)];
        s[0][mt] = __builtin_amdgcn_mfma_f32_16x16x32_bf16(ak0, q[0][0], s[0][mt], 0, 0, 0);
        s[0][mt] = __builtin_amdgcn_mfma_f32_16x16x32_bf16(ak1, q[0][1], s[0][mt], 0, 0, 0);
        s[1][mt] = __builtin_amdgcn_mfma_f32_16x16x32_bf16(ak0, q[1][0], s[1][mt], 0, 0, 0);
        s[1][mt] = __builtin_amdgcn_mfma_f32_16x16x32_bf16(ak1, q[1][1], s[1][mt], 0, 0, 0);
      }

      // ---- causal mask (only tiles straddling the diagonal)
      if (kv >= 2 * qt) {
        int ct = kv * 64;
#pragma unroll
        for (int rg = 0; rg < 2; ++rg)
#pragma unroll
          for (int mt = 0; mt < 4; ++mt)
#pragma unroll
            for (int r = 0; r < 4; ++r)
              if (ct + mt * 16 + quad * 4 + r > row0 + rg * 16 + l15) s[rg][mt][r] = -1e30f;
      }

      // ---- exp2 + in-register pack (V column permutation makes pa lane-local)
      bf16x8 pa[2][2];
#pragma unroll
      for (int rg = 0; rg < 2; ++rg)
#pragma unroll
        for (int k0 = 0; k0 < 2; ++k0)
#pragma unroll
          for (int hh = 0; hh < 2; ++hh)
#pragma unroll
            for (int r = 0; r < 4; ++r) {
              float p = fast_exp2(s[rg][2 * k0 + hh][r]);
              if (rg == 0) l0 += p; else l1 += p;
              pa[rg][k0][hh * 4 + r] = (bf16_t)p;
            }

      // ---- PV: each V fragment read once, feeds both row-groups
#pragma unroll
      for (int k0 = 0; k0 < 2; ++k0) {
#pragma unroll
        for (int dn = 0; dn < 4; ++dn) {
          bf16x8 bv = *(const bf16x8*)&vt[(dn * 16 + l15) * 64 + ((k0 * 32 + quad * 8) ^ swz)];
          o[0][dn] = __builtin_amdgcn_mfma_f32_16x16x32_bf16(pa[0][k0], bv, o[0][dn], 0, 0, 0);
          o[1][dn] = __builtin_amdgcn_mfma_f32_16x16x32_bf16(pa[1][k0], bv, o[1][dn], 0, 0, 0);
        }
      }
    }
  }

  // epilogue: reduce l across quads, normalize, write ctxb [B][T][H*DH]
  l0 += __shfl_xor(l0, 16, 64);
  l0 += __shfl_xor(l0, 32, 64);
  l1 += __shfl_xor(l1, 16, 64);
  l1 += __shfl_xor(l1, 32, 64);
  float inv0 = 1.0f / l0, inv1 = 1.0f / l1;
#pragma unroll
  for (int r = 0; r < 4; ++r) {
    float i0 = __shfl(inv0, quad * 4 + r, 64);
    float i1 = __shfl(inv1, quad * 4 + r, 64);
    int t0 = row0 + quad * 4 + r;
    int t1 = row0 + 16 + quad * 4 + r;
#pragma unroll
    for (int dn = 0; dn < 4; ++dn) {
      ctxb[(size_t)(b * T_ + t0) * D_ + h * 64 + dn * 16 + l15] = (bf16_t)(o[0][dn][r] * i0);
      ctxb[(size_t)(b * T_ + t1) * D_ + h * 64 + dn * 16 + l15] = (bf16_t)(o[1][dn][r] * i1);
    }
  }
}

// ---------------------------------------------------------------------- launcher
extern "C" void kernel_launch(void* const* d_in, const int* in_sizes, int n_in,
                              void* d_out, int out_size, void* d_ws, size_t ws_size,
                              hipStream_t stream) {
  const float* x = (const float*)d_in[0];
  const float* Wq = (const float*)d_in[1];
  const float* Wk = (const float*)d_in[2];
  const float* Wv = (const float*)d_in[3];
  const float* Wo = (const float*)d_in[4];
  float* out = (float*)d_out;

  char* ws = (char*)d_ws;
  size_t off = 0;
  bf16_t* xb = (bf16_t*)(ws + off); off += (size_t)B_ * T_ * D_ * 2;
  bf16_t* wqkvb = (bf16_t*)(ws + off); off += (size_t)3072 * 2048 * 2;
  bf16_t* wob = (bf16_t*)(ws + off); off += (size_t)2048 * 2048 * 2;
  bf16_t* qkv = (bf16_t*)(ws + off); off += (size_t)4096 * 3072 * 2;
  bf16_t* qr = (bf16_t*)(ws + off); off += (size_t)B_ * H_ * T_ * DH_ * 2;
  bf16_t* kr = (bf16_t*)(ws + off); off += (size_t)B_ * HKV_ * T_ * DH_ * 2;
  bf16_t* vtr = (bf16_t*)(ws + off); off += (size_t)B_ * HKV_ * T_ * DH_ * 2;
  bf16_t* ctxb = (bf16_t*)(ws + off); off += (size_t)B_ * T_ * D_ * 2;

  int nx = B_ * T_ * D_;
  cast_f32_bf16<<<nx / 8 / 256, 256, 0, stream>>>(x, xb, nx);
  transpose_wqkv<<<dim3(3072 / 64, 2048 / 64), 256, 0, stream>>>(Wq, Wk, Wv, wqkvb);
  transpose_w<<<dim3(2048 / 64, 2048 / 64), 256, 0, stream>>>(Wo, wob, 2048, 2048);

  gemm_bt<bf16_t><<<dim3(3072 / 128, 4096 / 128), 256, 0, stream>>>(xb, wqkvb, qkv, 4096, 3072, 2048);

  rope_qk<<<dim3(T_, B_), 256, 0, stream>>>(qkv, qr, kr);
  transpose_v<<<dim3(T_ / 64, HKV_, B_), 256, 0, stream>>>(qkv, vtr);

  flash_attn<<<dim3(16, H_, B_), 256, 0, stream>>>(qr, kr, vtr, ctxb);

  gemm_bt<float><<<dim3(2048 / 128, 4096 / 128), 256, 0, stream>>>(ctxb, wob, out, 4096, 2048, 2048);
}

// Round 9
// 347.973 us; speedup vs baseline: 1.0281x; 1.0281x over previous
//
#include <hip/hip_runtime.h>
#include <hip/hip_bf16.h>

// GQA + RoPE fused block for MI355X (gfx950).
// B=2, T=2048, D=2048, H=32, HKV=8, DH=64, G=4.
// bf16 MFMA 16x16x32 for QKV proj, attention, out proj. fp32 softmax/RoPE.
// Flash v13 = v12 (128-row single Q-tiles, 4 waves x 32 rows, 2x fragment
// reuse, conflict-free gld_lds staging, permuted+swizzled V, P-in-registers)
// + BALANCED qt MAPPING. r8 lesson: with grid 1024 = exact 4-blocks/CU
// residency (no backfill) and id = bx + 16h + 512b, a CU's co-resident
// blocks {id, id+256, id+512, id+768} all share bx (256 % 16 == 0) -> all
// same qt -> 1.88x deterministic per-CU imbalance (flash 104.7us, occ 10.8%).
// Fix: qt = (h<16 ? 15-bx : bx) rotated by 8 when b=1 -> each CU's four
// blocks have qt = {q, 15-q, q+8, 7-q}: sum nkv = 68 = exact mean, per-CU
// work constant. Bijection of bx per (h,b) preserved.
// r7: every wave active every iteration. r6: conflict-free staging. r5:
// merged-halves closed. r3: never pin min-waves. r4: no ptr-param lambdas.

typedef __bf16 bf16_t;
typedef __bf16 bf16x4 __attribute__((ext_vector_type(4)));
typedef __bf16 bf16x8 __attribute__((ext_vector_type(8)));
typedef float f32x4 __attribute__((ext_vector_type(4)));

#define B_ 2
#define T_ 2048
#define D_ 2048
#define H_ 32
#define HKV_ 8
#define DH_ 64

// 2^x via v_exp_f32 (avoid glibc __exp2f macro clash)
__device__ __forceinline__ float fast_exp2(float x) { return __builtin_amdgcn_exp2f(x); }

// async global->LDS, 16B per lane. LDS dest must be wave-uniform base; lane i
// deposits at base + 16*i (no padding allowed in the staged region).
__device__ __forceinline__ void gld_lds16(const bf16_t* g, bf16_t* l) {
  __builtin_amdgcn_global_load_lds((const __attribute__((address_space(1))) unsigned int*)g,
                                   (__attribute__((address_space(3))) unsigned int*)l, 16, 0, 0);
}

// ---------------------------------------------------------------- cast x -> bf16
__global__ __launch_bounds__(256) void cast_f32_bf16(const float* __restrict__ in,
                                                     bf16_t* __restrict__ out, int n) {
  int i = (blockIdx.x * 256 + threadIdx.x) * 8;
  if (i < n) {
    f32x4 a = *(const f32x4*)&in[i];
    f32x4 b = *(const f32x4*)&in[i + 4];
    bf16x8 o;
    o[0] = (bf16_t)a[0]; o[1] = (bf16_t)a[1]; o[2] = (bf16_t)a[2]; o[3] = (bf16_t)a[3];
    o[4] = (bf16_t)b[0]; o[5] = (bf16_t)b[1]; o[6] = (bf16_t)b[2]; o[7] = (bf16_t)b[3];
    *(bf16x8*)&out[i] = o;
  }
}

// ------------------------------------------- transpose + cast: W[K][N] -> Wt[N][K]
__global__ __launch_bounds__(256) void transpose_w(const float* __restrict__ W,
                                                   bf16_t* __restrict__ Wt, int K, int N) {
  __shared__ float tile[64][65];
  int n0 = blockIdx.x * 64, k0 = blockIdx.y * 64;
  int tid = threadIdx.x;
  for (int i = tid; i < 4096; i += 256) {
    int r = i >> 6, c = i & 63;
    tile[r][c] = W[(size_t)(k0 + r) * N + n0 + c];
  }
  __syncthreads();
  for (int i = tid; i < 4096; i += 256) {
    int r = i >> 6, c = i & 63;
    Wt[(size_t)(n0 + r) * K + k0 + c] = (bf16_t)tile[c][r];
  }
}

// --------------------- fused transpose+cast of Wq|Wk|Wv into wqkvb[3072][2048]
__global__ __launch_bounds__(256) void transpose_wqkv(const float* __restrict__ Wq,
                                                      const float* __restrict__ Wk,
                                                      const float* __restrict__ Wv,
                                                      bf16_t* __restrict__ Wt) {
  __shared__ float tile[64][65];
  int n0 = blockIdx.x * 64, k0 = blockIdx.y * 64;
  const float* W;
  int srcN, col;
  if (n0 < 2048) { W = Wq; srcN = 2048; col = n0; }
  else if (n0 < 2560) { W = Wk; srcN = 512; col = n0 - 2048; }
  else { W = Wv; srcN = 512; col = n0 - 2560; }
  int tid = threadIdx.x;
  for (int i = tid; i < 4096; i += 256) {
    int r = i >> 6, c = i & 63;
    tile[r][c] = W[(size_t)(k0 + r) * srcN + col + c];
  }
  __syncthreads();
  for (int i = tid; i < 4096; i += 256) {
    int r = i >> 6, c = i & 63;
    Wt[(size_t)(n0 + r) * 2048 + k0 + c] = (bf16_t)tile[c][r];
  }
}

// ---------------------------------------------------------------- bf16 MFMA GEMM
// m97 structure, BK=64 as two concatenated stride-32 sub-blocks: keeps the
// bank-optimal 32-elem row stride and gld_lds16 lane order; halves barriers.
template <typename OutT>
__global__ __launch_bounds__(256) void gemm_bt(const bf16_t* __restrict__ A,
                                               const bf16_t* __restrict__ Bt,
                                               OutT* __restrict__ C, int M, int N, int K) {
  __shared__ __align__(16) bf16_t As[2 * 128 * 32];
  __shared__ __align__(16) bf16_t Bs[2 * 128 * 32];
  int tid = threadIdx.x;
  int lane = tid & 63;
  int wave = tid >> 6;
  int l15 = lane & 15;
  int quad = lane >> 4;
  int m0 = blockIdx.y * 128;
  int n0 = blockIdx.x * 128;
  int wrow = (wave >> 1) * 64;
  int wcol = (wave & 1) * 64;

  f32x4 acc[4][4] = {};

  for (int kc = 0; kc < K; kc += 64) {
#pragma unroll
    for (int kk = 0; kk < 2; ++kk) {
#pragma unroll
      for (int c = 0; c < 2; ++c) {
        int linear = c * 256 + tid;
        int r = linear >> 2, seg = linear & 3;
        gld_lds16(&A[(size_t)(m0 + r) * K + kc + kk * 32 + seg * 8],
                  &As[kk * 4096 + (size_t)(c * 256 + wave * 64) * 8]);
        gld_lds16(&Bt[(size_t)(n0 + r) * K + kc + kk * 32 + seg * 8],
                  &Bs[kk * 4096 + (size_t)(c * 256 + wave * 64) * 8]);
      }
    }
    __syncthreads();
#pragma unroll
    for (int kk = 0; kk < 2; ++kk) {
      bf16x8 af[4], bfr[4];
#pragma unroll
      for (int mi = 0; mi < 4; ++mi)
        af[mi] = *(const bf16x8*)&As[kk * 4096 + (wrow + mi * 16 + l15) * 32 + quad * 8];
#pragma unroll
      for (int ni = 0; ni < 4; ++ni)
        bfr[ni] = *(const bf16x8*)&Bs[kk * 4096 + (wcol + ni * 16 + l15) * 32 + quad * 8];
#pragma unroll
      for (int mi = 0; mi < 4; ++mi)
#pragma unroll
        for (int ni = 0; ni < 4; ++ni)
          acc[mi][ni] = __builtin_amdgcn_mfma_f32_16x16x32_bf16(af[mi], bfr[ni], acc[mi][ni], 0, 0, 0);
    }
    __syncthreads();
  }
#pragma unroll
  for (int mi = 0; mi < 4; ++mi) {
#pragma unroll
    for (int ni = 0; ni < 4; ++ni) {
#pragma unroll
      for (int r = 0; r < 4; ++r) {
        int m = m0 + wrow + mi * 16 + quad * 4 + r;
        int n = n0 + wcol + ni * 16 + l15;
        C[(size_t)m * N + n] = (OutT)acc[mi][ni][r];
      }
    }
  }
}

// ------------------------------------------------- RoPE on q,k + head-major relayout
// qkv rows (bf16): [q 2048 | k 512 | v 512]. qr: [B][H][T][DH], kr: [B][HKV][T][DH].
// Q is pre-scaled by log2(e)/sqrt(64) so flash's softmax is bare exp2(q.k).
// K rows are stored SLOT-SWIZZLED (elem j -> j ^ ((t&7)<<3), 16B granules) so
// flash's linear gld_lds16 deposit lands in the bank-conflict-free layout.
__global__ __launch_bounds__(256) void rope_qk(const bf16_t* __restrict__ qkv,
                                               bf16_t* __restrict__ qr,
                                               bf16_t* __restrict__ kr) {
  int t = blockIdx.x, b = blockIdx.y;
  int tid = threadIdx.x;
  const bf16_t* row = qkv + (size_t)(b * T_ + t) * 3072;
  const float LN1E4_over32 = 9.210340371976184f / 32.0f;
  const float QSC = 1.44269504088896f * 0.125f;  // log2(e)/sqrt(64)
  int ksw = (t & 7) << 3;
  for (int i = tid; i < 1024 + 256; i += 256) {
    bool isq = i < 1024;
    int ii = isq ? i : i - 1024;
    int hh = ii >> 5, j = ii & 31;
    int base = isq ? 0 : 2048;
    float inv = __expf(-(float)j * LN1E4_over32);
    float fr = (float)t * inv;
    float sn, cs;
    sincosf(fr, &sn, &cs);
    float x1 = (float)row[base + hh * 64 + j];
    float x2 = (float)row[base + hh * 64 + j + 32];
    float o1 = x1 * cs - x2 * sn;
    float o2 = x2 * cs + x1 * sn;
    if (isq) {
      size_t o = ((size_t)(b * H_ + hh) * T_ + t) * DH_;
      qr[o + j] = (bf16_t)(o1 * QSC);
      qr[o + j + 32] = (bf16_t)(o2 * QSC);
    } else {
      size_t o = ((size_t)(b * HKV_ + hh) * T_ + t) * DH_;
      kr[o + (j ^ ksw)] = (bf16_t)o1;
      kr[o + ((j + 32) ^ ksw)] = (bf16_t)o2;
    }
  }
}

// ----------------------------------------- V: transpose to [B][HKV][DH][T] (bf16)
// Two layered transforms on the kv-column index within each 64-wide tile:
// (1) PERMUTE f(n) = 32*b5 + 16*b2 + 4*(b4b3) + (b1b0) so flash's PV A-fragment
//     (P values) is lane-local after the swapped QK^T (see v6 notes);
// (2) SLOT-SWIZZLE col ^= (dd&7)<<3 (16B granules) so flash's linear gld_lds16
//     deposit of each 128B row lands bank-conflict-free for the swizzled reads.
__global__ __launch_bounds__(256) void transpose_v(const bf16_t* __restrict__ qkv,
                                                   bf16_t* __restrict__ vtr) {
  __shared__ __align__(16) bf16_t tile[64][72];
  int t0 = blockIdx.x * 64;
  int hk = blockIdx.y;
  int b = blockIdx.z;
  int tid = threadIdx.x;
  for (int i = tid; i < 512; i += 256) {
    int r = i >> 3, s = i & 7;
    *(bf16x8*)&tile[r][s * 8] =
        *(const bf16x8*)&qkv[(size_t)(b * T_ + t0 + r) * 3072 + 2560 + hk * 64 + s * 8];
  }
  __syncthreads();
  for (int i = tid; i < 4096; i += 256) {
    int dd = i >> 6, tt = i & 63;
    int src = (tt & 32) | ((tt & 4) << 2) | ((tt & 24) >> 1) | (tt & 3);
    int dst = tt ^ ((dd & 7) << 3);
    vtr[((size_t)(b * HKV_ + hk) * DH_ + dd) * T_ + t0 + dst] = tile[src][dd];
  }
}

// ---------------------------------------------------------------- flash attention v13
// grid (16, H, B) = 1024 blocks, 256 threads (4 waves). Block handles ONE
// 128-row Q-tile; wave owns 32 q-rows as two 16-row fragments -> each K/V LDS
// fragment read feeds TWO MFMAs; all waves active every iteration.
// BALANCED qt MAPPING (r8): co-resident blocks {id, id+256, id+512, id+768}
// differ in (h-bit4, b); qt = (h<16 ? 15-bx : bx) rotated by 8 for b=1 gives
// each CU qt = {q, 15-q, q+8, 7-q} -> per-CU work exactly the mean (68 tiles).
// Fully-masked wave-iterations skipped wave-uniformly (exp2(-1e30)=0 exact).
// Staging via global_load_lds: linear LDS dest, pre-swizzled global sources;
// one barrier per kv tile (implicit vmcnt(0) drain orders deposits & frees the
// previous buffer). 32 KB LDS.
__global__ __launch_bounds__(256) void flash_attn(const bf16_t* __restrict__ qr,
                                                  const bf16_t* __restrict__ kr,
                                                  const bf16_t* __restrict__ vtr,
                                                  bf16_t* __restrict__ ctxb) {
  __shared__ __align__(16) bf16_t Ks[2][64 * 64];
  __shared__ __align__(16) bf16_t Vt[2][64 * 64];
  int tid = threadIdx.x;
  int lane = tid & 63;
  int wave = tid >> 6;
  int l15 = lane & 15, quad = lane >> 4;
  int swz = (l15 & 7) * 8;
  int bx = blockIdx.x, h = blockIdx.y, b = blockIdx.z;
  int rot = b ? 8 : 0;
  int qt = (h < 16) ? ((15 - bx + rot) & 15) : ((bx + rot) & 15);
  int nkv = 2 * qt + 2;
  int kvh = h >> 2;
  int wrow = wave * 32;  // wave's first row within the 128-row tile
  int row0 = qt * 128 + wrow;

  const bf16_t* qb = qr + ((size_t)(b * H_ + h) * T_ + row0) * DH_;
  const bf16_t* kbase = kr + (size_t)(b * HKV_ + kvh) * T_ * DH_;
  const bf16_t* vbase = vtr + (size_t)(b * HKV_ + kvh) * DH_ * T_;

  // Q fragments (B-operand layout: lane l15 = qrow-in-frag, k = quad*8+j)
  bf16x8 q[2][2];
#pragma unroll
  for (int rg = 0; rg < 2; ++rg)
#pragma unroll
    for (int k0 = 0; k0 < 2; ++k0)
      q[rg][k0] = *(const bf16x8*)&qb[(rg * 16 + l15) * 64 + k0 * 32 + quad * 8];

  f32x4 o[2][4] = {};
  float l0 = 0.f, l1 = 0.f;

  // async stage of one K/V tile (8 KB each) into buffer bf: 4 gld_lds16/thread.
  auto stage = [&](int kv, int bf) {
#pragma unroll
    for (int c = 0; c < 2; ++c) {
      int idx = c * 256 + tid;
      bf16_t* dst = &Ks[bf][(c * 256 + wave * 64) * 8];
      gld_lds16(&kbase[(size_t)kv * 4096 + idx * 8], dst);
      bf16_t* dstv = &Vt[bf][(c * 256 + wave * 64) * 8];
      gld_lds16(&vbase[(size_t)(idx >> 3) * T_ + kv * 64 + (idx & 7) * 8], dstv);
    }
  };
  stage(0, 0);

  for (int kv = 0; kv < nkv; ++kv) {
    const bf16_t* ks = Ks[kv & 1];
    const bf16_t* vt = Vt[kv & 1];
    // barrier drains vmcnt -> deposits for tile kv landed (all waves), and all
    // waves finished compute(kv-1) -> buf^1 is free for the next prefetch.
    __syncthreads();
    if (kv + 1 < nkv) stage(kv + 1, (kv + 1) & 1);

    // skip wave-iterations where every element is causally masked (wave-uniform)
    if (kv * 64 <= row0 + 31) {
      // ---- QK^T: each K fragment read once, feeds both row-groups
      f32x4 s[2][4] = {};
#pragma unroll
      for (int mt = 0; mt < 4; ++mt) {
        bf16x8 ak0 = *(const bf16x8*)&ks[(mt * 16 + l15) * 64 + ((quad * 8) ^ swz)];
        bf16x8 ak1 = *(const bf16x8*)&ks[(mt * 16 + l15) * 64 + ((32 + quad * 8) ^ swz)];
        s[0][mt] = __builtin_amdgcn_mfma_f32_16x16x32_bf16(ak0, q[0][0], s[0][mt], 0, 0, 0);
        s[0][mt] = __builtin_amdgcn_mfma_f32_16x16x32_bf16(ak1, q[0][1], s[0][mt], 0, 0, 0);
        s[1][mt] = __builtin_amdgcn_mfma_f32_16x16x32_bf16(ak0, q[1][0], s[1][mt], 0, 0, 0);
        s[1][mt] = __builtin_amdgcn_mfma_f32_16x16x32_bf16(ak1, q[1][1], s[1][mt], 0, 0, 0);
      }

      // ---- causal mask (only tiles straddling the diagonal)
      if (kv >= 2 * qt) {
        int ct = kv * 64;
#pragma unroll
        for (int rg = 0; rg < 2; ++rg)
#pragma unroll
          for (int mt = 0; mt < 4; ++mt)
#pragma unroll
            for (int r = 0; r < 4; ++r)
              if (ct + mt * 16 + quad * 4 + r > row0 + rg * 16 + l15) s[rg][mt][r] = -1e30f;
      }

      // ---- exp2 + in-register pack (V column permutation makes pa lane-local)
      bf16x8 pa[2][2];
#pragma unroll
      for (int rg = 0; rg < 2; ++rg)
#pragma unroll
        for (int k0 = 0; k0 < 2; ++k0)
#pragma unroll
          for (int hh = 0; hh < 2; ++hh)
#pragma unroll
            for (int r = 0; r < 4; ++r) {
              float p = fast_exp2(s[rg][2 * k0 + hh][r]);
              if (rg == 0) l0 += p; else l1 += p;
              pa[rg][k0][hh * 4 + r] = (bf16_t)p;
            }

      // ---- PV: each V fragment read once, feeds both row-groups
#pragma unroll
      for (int k0 = 0; k0 < 2; ++k0) {
#pragma unroll
        for (int dn = 0; dn < 4; ++dn) {
          bf16x8 bv = *(const bf16x8*)&vt[(dn * 16 + l15) * 64 + ((k0 * 32 + quad * 8) ^ swz)];
          o[0][dn] = __builtin_amdgcn_mfma_f32_16x16x32_bf16(pa[0][k0], bv, o[0][dn], 0, 0, 0);
          o[1][dn] = __builtin_amdgcn_mfma_f32_16x16x32_bf16(pa[1][k0], bv, o[1][dn], 0, 0, 0);
        }
      }
    }
  }

  // epilogue: reduce l across quads, normalize, write ctxb [B][T][H*DH]
  l0 += __shfl_xor(l0, 16, 64);
  l0 += __shfl_xor(l0, 32, 64);
  l1 += __shfl_xor(l1, 16, 64);
  l1 += __shfl_xor(l1, 32, 64);
  float inv0 = 1.0f / l0, inv1 = 1.0f / l1;
#pragma unroll
  for (int r = 0; r < 4; ++r) {
    float i0 = __shfl(inv0, quad * 4 + r, 64);
    float i1 = __shfl(inv1, quad * 4 + r, 64);
    int t0 = row0 + quad * 4 + r;
    int t1 = row0 + 16 + quad * 4 + r;
#pragma unroll
    for (int dn = 0; dn < 4; ++dn) {
      ctxb[(size_t)(b * T_ + t0) * D_ + h * 64 + dn * 16 + l15] = (bf16_t)(o[0][dn][r] * i0);
      ctxb[(size_t)(b * T_ + t1) * D_ + h * 64 + dn * 16 + l15] = (bf16_t)(o[1][dn][r] * i1);
    }
  }
}

// ---------------------------------------------------------------------- launcher
extern "C" void kernel_launch(void* const* d_in, const int* in_sizes, int n_in,
                              void* d_out, int out_size, void* d_ws, size_t ws_size,
                              hipStream_t stream) {
  const float* x = (const float*)d_in[0];
  const float* Wq = (const float*)d_in[1];
  const float* Wk = (const float*)d_in[2];
  const float* Wv = (const float*)d_in[3];
  const float* Wo = (const float*)d_in[4];
  float* out = (float*)d_out;

  char* ws = (char*)d_ws;
  size_t off = 0;
  bf16_t* xb = (bf16_t*)(ws + off); off += (size_t)B_ * T_ * D_ * 2;
  bf16_t* wqkvb = (bf16_t*)(ws + off); off += (size_t)3072 * 2048 * 2;
  bf16_t* wob = (bf16_t*)(ws + off); off += (size_t)2048 * 2048 * 2;
  bf16_t* qkv = (bf16_t*)(ws + off); off += (size_t)4096 * 3072 * 2;
  bf16_t* qr = (bf16_t*)(ws + off); off += (size_t)B_ * H_ * T_ * DH_ * 2;
  bf16_t* kr = (bf16_t*)(ws + off); off += (size_t)B_ * HKV_ * T_ * DH_ * 2;
  bf16_t* vtr = (bf16_t*)(ws + off); off += (size_t)B_ * HKV_ * T_ * DH_ * 2;
  bf16_t* ctxb = (bf16_t*)(ws + off); off += (size_t)B_ * T_ * D_ * 2;

  int nx = B_ * T_ * D_;
  cast_f32_bf16<<<nx / 8 / 256, 256, 0, stream>>>(x, xb, nx);
  transpose_wqkv<<<dim3(3072 / 64, 2048 / 64), 256, 0, stream>>>(Wq, Wk, Wv, wqkvb);
  transpose_w<<<dim3(2048 / 64, 2048 / 64), 256, 0, stream>>>(Wo, wob, 2048, 2048);

  gemm_bt<bf16_t><<<dim3(3072 / 128, 4096 / 128), 256, 0, stream>>>(xb, wqkvb, qkv, 4096, 3072, 2048);

  rope_qk<<<dim3(T_, B_), 256, 0, stream>>>(qkv, qr, kr);
  transpose_v<<<dim3(T_ / 64, HKV_, B_), 256, 0, stream>>>(qkv, vtr);

  flash_attn<<<dim3(16, H_, B_), 256, 0, stream>>>(qr, kr, vtr, ctxb);

  gemm_bt<float><<<dim3(2048 / 128, 4096 / 128), 256, 0, stream>>>(ctxb, wob, out, 4096, 2048, 2048);
}

// Round 10
// 322.236 us; speedup vs baseline: 1.1102x; 1.0799x over previous
//
#include <hip/hip_runtime.h>
#include <hip/hip_bf16.h>

// GQA + RoPE fused block for MI355X (gfx950).
// B=2, T=2048, D=2048, H=32, HKV=8, DH=64, G=4.
// bf16 MFMA 16x16x32 for QKV proj, attention, out proj. fp32 softmax/RoPE.
// Flash v10 (FINAL): 64-row Q-tile pairs (constant 33 iters/block, grid 1024 =
// 4 blocks/CU), conflict-free global_load_lds staging into slot-swizzled
// [64][64] tiles (producers pre-swizzle), permuted V -> P stays in registers,
// 1 barrier per kv tile. Measured 68.8us, ~90% at the ds_read_b128 throughput
// floor. Read-reuse restructures falsified 4x (r2 grid-halving, r5 sw-merge,
// r7 wave-split, r9 tile+balance): every embodiment pays more in occupancy/
// balance/VALU than the LDS bytes it saves. Flash closed at v10.
// GEMMs: + XCD-chunked block swizzle (T1, bijective since nwg%8==0): probes
// whether B-panel re-reads are L2-locality-sensitive.
// r3: never pin min-waves. r4: no ptr-param lambdas.

typedef __bf16 bf16_t;
typedef __bf16 bf16x4 __attribute__((ext_vector_type(4)));
typedef __bf16 bf16x8 __attribute__((ext_vector_type(8)));
typedef float f32x4 __attribute__((ext_vector_type(4)));

#define B_ 2
#define T_ 2048
#define D_ 2048
#define H_ 32
#define HKV_ 8
#define DH_ 64

// 2^x via v_exp_f32 (avoid glibc __exp2f macro clash)
__device__ __forceinline__ float fast_exp2(float x) { return __builtin_amdgcn_exp2f(x); }

// async global->LDS, 16B per lane. LDS dest must be wave-uniform base; lane i
// deposits at base + 16*i (no padding allowed in the staged region).
__device__ __forceinline__ void gld_lds16(const bf16_t* g, bf16_t* l) {
  __builtin_amdgcn_global_load_lds((const __attribute__((address_space(1))) unsigned int*)g,
                                   (__attribute__((address_space(3))) unsigned int*)l, 16, 0, 0);
}

// ---------------------------------------------------------------- cast x -> bf16
__global__ __launch_bounds__(256) void cast_f32_bf16(const float* __restrict__ in,
                                                     bf16_t* __restrict__ out, int n) {
  int i = (blockIdx.x * 256 + threadIdx.x) * 8;
  if (i < n) {
    f32x4 a = *(const f32x4*)&in[i];
    f32x4 b = *(const f32x4*)&in[i + 4];
    bf16x8 o;
    o[0] = (bf16_t)a[0]; o[1] = (bf16_t)a[1]; o[2] = (bf16_t)a[2]; o[3] = (bf16_t)a[3];
    o[4] = (bf16_t)b[0]; o[5] = (bf16_t)b[1]; o[6] = (bf16_t)b[2]; o[7] = (bf16_t)b[3];
    *(bf16x8*)&out[i] = o;
  }
}

// ------------------------------------------- transpose + cast: W[K][N] -> Wt[N][K]
__global__ __launch_bounds__(256) void transpose_w(const float* __restrict__ W,
                                                   bf16_t* __restrict__ Wt, int K, int N) {
  __shared__ float tile[64][65];
  int n0 = blockIdx.x * 64, k0 = blockIdx.y * 64;
  int tid = threadIdx.x;
  for (int i = tid; i < 4096; i += 256) {
    int r = i >> 6, c = i & 63;
    tile[r][c] = W[(size_t)(k0 + r) * N + n0 + c];
  }
  __syncthreads();
  for (int i = tid; i < 4096; i += 256) {
    int r = i >> 6, c = i & 63;
    Wt[(size_t)(n0 + r) * K + k0 + c] = (bf16_t)tile[c][r];
  }
}

// --------------------- fused transpose+cast of Wq|Wk|Wv into wqkvb[3072][2048]
__global__ __launch_bounds__(256) void transpose_wqkv(const float* __restrict__ Wq,
                                                      const float* __restrict__ Wk,
                                                      const float* __restrict__ Wv,
                                                      bf16_t* __restrict__ Wt) {
  __shared__ float tile[64][65];
  int n0 = blockIdx.x * 64, k0 = blockIdx.y * 64;
  const float* W;
  int srcN, col;
  if (n0 < 2048) { W = Wq; srcN = 2048; col = n0; }
  else if (n0 < 2560) { W = Wk; srcN = 512; col = n0 - 2048; }
  else { W = Wv; srcN = 512; col = n0 - 2560; }
  int tid = threadIdx.x;
  for (int i = tid; i < 4096; i += 256) {
    int r = i >> 6, c = i & 63;
    tile[r][c] = W[(size_t)(k0 + r) * srcN + col + c];
  }
  __syncthreads();
  for (int i = tid; i < 4096; i += 256) {
    int r = i >> 6, c = i & 63;
    Wt[(size_t)(n0 + r) * 2048 + k0 + c] = (bf16_t)tile[c][r];
  }
}

// ---------------------------------------------------------------- bf16 MFMA GEMM
// m97 structure, BK=64 as two concatenated stride-32 sub-blocks. XCD-chunked
// block swizzle (T1): co-resident remap so consecutive blocks per XCD share
// A-panels and walk B-panels (bijective: both launches have nwg % 8 == 0).
template <typename OutT>
__global__ __launch_bounds__(256) void gemm_bt(const bf16_t* __restrict__ A,
                                               const bf16_t* __restrict__ Bt,
                                               OutT* __restrict__ C, int M, int N, int K) {
  __shared__ __align__(16) bf16_t As[2 * 128 * 32];
  __shared__ __align__(16) bf16_t Bs[2 * 128 * 32];
  int tid = threadIdx.x;
  int lane = tid & 63;
  int wave = tid >> 6;
  int l15 = lane & 15;
  int quad = lane >> 4;
  // XCD-aware swizzle of the flattened workgroup id (nwg % 8 == 0 guaranteed).
  int nwg = gridDim.x * gridDim.y;
  int id = blockIdx.y * gridDim.x + blockIdx.x;
  int cpx = nwg >> 3;
  int sid = (id & 7) * cpx + (id >> 3);
  int bx = sid % gridDim.x;
  int by = sid / gridDim.x;
  int m0 = by * 128;
  int n0 = bx * 128;
  int wrow = (wave >> 1) * 64;
  int wcol = (wave & 1) * 64;

  f32x4 acc[4][4] = {};

  for (int kc = 0; kc < K; kc += 64) {
#pragma unroll
    for (int kk = 0; kk < 2; ++kk) {
#pragma unroll
      for (int c = 0; c < 2; ++c) {
        int linear = c * 256 + tid;
        int r = linear >> 2, seg = linear & 3;
        gld_lds16(&A[(size_t)(m0 + r) * K + kc + kk * 32 + seg * 8],
                  &As[kk * 4096 + (size_t)(c * 256 + wave * 64) * 8]);
        gld_lds16(&Bt[(size_t)(n0 + r) * K + kc + kk * 32 + seg * 8],
                  &Bs[kk * 4096 + (size_t)(c * 256 + wave * 64) * 8]);
      }
    }
    __syncthreads();
#pragma unroll
    for (int kk = 0; kk < 2; ++kk) {
      bf16x8 af[4], bfr[4];
#pragma unroll
      for (int mi = 0; mi < 4; ++mi)
        af[mi] = *(const bf16x8*)&As[kk * 4096 + (wrow + mi * 16 + l15) * 32 + quad * 8];
#pragma unroll
      for (int ni = 0; ni < 4; ++ni)
        bfr[ni] = *(const bf16x8*)&Bs[kk * 4096 + (wcol + ni * 16 + l15) * 32 + quad * 8];
#pragma unroll
      for (int mi = 0; mi < 4; ++mi)
#pragma unroll
        for (int ni = 0; ni < 4; ++ni)
          acc[mi][ni] = __builtin_amdgcn_mfma_f32_16x16x32_bf16(af[mi], bfr[ni], acc[mi][ni], 0, 0, 0);
    }
    __syncthreads();
  }
#pragma unroll
  for (int mi = 0; mi < 4; ++mi) {
#pragma unroll
    for (int ni = 0; ni < 4; ++ni) {
#pragma unroll
      for (int r = 0; r < 4; ++r) {
        int m = m0 + wrow + mi * 16 + quad * 4 + r;
        int n = n0 + wcol + ni * 16 + l15;
        C[(size_t)m * N + n] = (OutT)acc[mi][ni][r];
      }
    }
  }
}

// ------------------------------------------------- RoPE on q,k + head-major relayout
// qkv rows (bf16): [q 2048 | k 512 | v 512]. qr: [B][H][T][DH], kr: [B][HKV][T][DH].
// Q is pre-scaled by log2(e)/sqrt(64) so flash's softmax is bare exp2(q.k).
// K rows are stored SLOT-SWIZZLED (elem j -> j ^ ((t&7)<<3), 16B granules) so
// flash's linear gld_lds16 deposit lands in the bank-conflict-free layout.
__global__ __launch_bounds__(256) void rope_qk(const bf16_t* __restrict__ qkv,
                                               bf16_t* __restrict__ qr,
                                               bf16_t* __restrict__ kr) {
  int t = blockIdx.x, b = blockIdx.y;
  int tid = threadIdx.x;
  const bf16_t* row = qkv + (size_t)(b * T_ + t) * 3072;
  const float LN1E4_over32 = 9.210340371976184f / 32.0f;
  const float QSC = 1.44269504088896f * 0.125f;  // log2(e)/sqrt(64)
  int ksw = (t & 7) << 3;
  for (int i = tid; i < 1024 + 256; i += 256) {
    bool isq = i < 1024;
    int ii = isq ? i : i - 1024;
    int hh = ii >> 5, j = ii & 31;
    int base = isq ? 0 : 2048;
    float inv = __expf(-(float)j * LN1E4_over32);
    float fr = (float)t * inv;
    float sn, cs;
    sincosf(fr, &sn, &cs);
    float x1 = (float)row[base + hh * 64 + j];
    float x2 = (float)row[base + hh * 64 + j + 32];
    float o1 = x1 * cs - x2 * sn;
    float o2 = x2 * cs + x1 * sn;
    if (isq) {
      size_t o = ((size_t)(b * H_ + hh) * T_ + t) * DH_;
      qr[o + j] = (bf16_t)(o1 * QSC);
      qr[o + j + 32] = (bf16_t)(o2 * QSC);
    } else {
      size_t o = ((size_t)(b * HKV_ + hh) * T_ + t) * DH_;
      kr[o + (j ^ ksw)] = (bf16_t)o1;
      kr[o + ((j + 32) ^ ksw)] = (bf16_t)o2;
    }
  }
}

// ----------------------------------------- V: transpose to [B][HKV][DH][T] (bf16)
// Two layered transforms on the kv-column index within each 64-wide tile:
// (1) PERMUTE f(n) = 32*b5 + 16*b2 + 4*(b4b3) + (b1b0) so flash's PV A-fragment
//     (P values) is lane-local after the swapped QK^T (see v6 notes);
// (2) SLOT-SWIZZLE col ^= (dd&7)<<3 (16B granules) so flash's linear gld_lds16
//     deposit of each 128B row lands bank-conflict-free for the swizzled reads.
__global__ __launch_bounds__(256) void transpose_v(const bf16_t* __restrict__ qkv,
                                                   bf16_t* __restrict__ vtr) {
  __shared__ __align__(16) bf16_t tile[64][72];
  int t0 = blockIdx.x * 64;
  int hk = blockIdx.y;
  int b = blockIdx.z;
  int tid = threadIdx.x;
  for (int i = tid; i < 512; i += 256) {
    int r = i >> 3, s = i & 7;
    *(bf16x8*)&tile[r][s * 8] =
        *(const bf16x8*)&qkv[(size_t)(b * T_ + t0 + r) * 3072 + 2560 + hk * 64 + s * 8];
  }
  __syncthreads();
  for (int i = tid; i < 4096; i += 256) {
    int dd = i >> 6, tt = i & 63;
    int src = (tt & 32) | ((tt & 4) << 2) | ((tt & 24) >> 1) | (tt & 3);
    int dst = tt ^ ((dd & 7) << 3);
    vtr[((size_t)(b * HKV_ + hk) * DH_ + dd) * T_ + t0 + dst] = tile[src][dd];
  }
}

// One half's QK^T -> mask -> exp2 -> in-register pack -> PV.
// P never touches LDS (permuted V makes the PV A-fragment lane-local).
// LDS tiles are [64][64] with 16B slots XOR-swizzled by row&7 (swz = (l15&7)*8).
#define DO_HALF(QF, O, LACC, DOMASK, KS, VT)                                              \
  {                                                                                       \
    f32x4 s_[4] = {};                                                                     \
    _Pragma("unroll") for (int mt = 0; mt < 4; ++mt) {                                    \
      bf16x8 ak0 = *(const bf16x8*)&KS[(mt * 16 + l15) * 64 + ((quad * 8) ^ swz)];        \
      bf16x8 ak1 = *(const bf16x8*)&KS[(mt * 16 + l15) * 64 + ((32 + quad * 8) ^ swz)];   \
      s_[mt] = __builtin_amdgcn_mfma_f32_16x16x32_bf16(ak0, QF[0], s_[mt], 0, 0, 0);      \
      s_[mt] = __builtin_amdgcn_mfma_f32_16x16x32_bf16(ak1, QF[1], s_[mt], 0, 0, 0);      \
    }                                                                                     \
    if (DOMASK) {                                                                         \
      _Pragma("unroll") for (int mt = 0; mt < 4; ++mt)                                    \
          _Pragma("unroll") for (int r = 0; r < 4; ++r) if (mt * 16 + quad * 4 + r >      \
                                                            wave * 16 + l15)              \
              s_[mt][r] = -1e30f;                                                         \
    }                                                                                     \
    _Pragma("unroll") for (int k0 = 0; k0 < 2; ++k0) {                                    \
      bf16x8 pa;                                                                          \
      _Pragma("unroll") for (int hh = 0; hh < 2; ++hh)                                    \
          _Pragma("unroll") for (int r = 0; r < 4; ++r) {                                 \
        float p = fast_exp2(s_[2 * k0 + hh][r]);                                          \
        LACC += p;                                                                        \
        pa[hh * 4 + r] = (bf16_t)p;                                                       \
      }                                                                                   \
      _Pragma("unroll") for (int dn = 0; dn < 4; ++dn) {                                  \
        bf16x8 bv =                                                                       \
            *(const bf16x8*)&VT[(dn * 16 + l15) * 64 + ((k0 * 32 + quad * 8) ^ swz)];     \
        O[dn] = __builtin_amdgcn_mfma_f32_16x16x32_bf16(pa, bv, O[dn], 0, 0, 0);          \
      }                                                                                   \
    }                                                                                     \
  }

// ---------------------------------------------------------------- flash attention v10
// grid (16 pairs, H, B), 256 threads (4 waves). Block handles Q-tile pair
// (qtA=i, qtB=31-i), 64 rows each. Staging via global_load_lds: linear LDS
// dest, pre-swizzled global sources. One barrier per kv tile; __syncthreads'
// implicit vmcnt(0) drain guarantees (a) this wave's deposits for tile kv have
// landed, and (b) all waves finished compute(kv-1), freeing buf^1 for the
// prefetch issued right after the barrier. 32 KB LDS -> 4 blocks/CU (grid-capped).
__global__ __launch_bounds__(256) void flash_attn(const bf16_t* __restrict__ qr,
                                                  const bf16_t* __restrict__ kr,
                                                  const bf16_t* __restrict__ vtr,
                                                  bf16_t* __restrict__ ctxb) {
  __shared__ __align__(16) bf16_t Ks[2][64 * 64];
  __shared__ __align__(16) bf16_t Vt[2][64 * 64];
  int tid = threadIdx.x;
  int lane = tid & 63;
  int wave = tid >> 6;
  int l15 = lane & 15, quad = lane >> 4;
  int swz = (l15 & 7) * 8;
  int pair = blockIdx.x, h = blockIdx.y, b = blockIdx.z;
  int qtA = pair, qtB = 31 - pair;  // 64-row Q tiles; qtA < qtB always
  int nkvA = qtA + 1, nkvB = qtB + 1;
  int kvh = h >> 2;

  const bf16_t* qbA = qr + ((size_t)(b * H_ + h) * T_ + qtA * 64 + wave * 16) * DH_;
  const bf16_t* qbB = qr + ((size_t)(b * H_ + h) * T_ + qtB * 64 + wave * 16) * DH_;
  const bf16_t* kbase = kr + (size_t)(b * HKV_ + kvh) * T_ * DH_;
  const bf16_t* vbase = vtr + (size_t)(b * HKV_ + kvh) * DH_ * T_;

  // Q fragments (B-operand layout: lane l15 = qrow, k = quad*8+j), both halves
  bf16x8 qA[2], qB[2];
#pragma unroll
  for (int k0 = 0; k0 < 2; ++k0) {
    qA[k0] = *(const bf16x8*)&qbA[l15 * 64 + k0 * 32 + quad * 8];
    qB[k0] = *(const bf16x8*)&qbB[l15 * 64 + k0 * 32 + quad * 8];
  }

  f32x4 oA[4] = {}, oB[4] = {};
  float lA = 0.f, lB = 0.f;

  // async stage of one K/V tile (8 KB each) into buffer bf: 4 gld_lds16/thread.
  // K source is linear (kr rows pre-swizzled); V rows strided by T.
  auto stage = [&](int kv, int bf) {
#pragma unroll
    for (int c = 0; c < 2; ++c) {
      int idx = c * 256 + tid;
      bf16_t* dst = &Ks[bf][(c * 256 + wave * 64) * 8];
      gld_lds16(&kbase[(size_t)kv * 4096 + idx * 8], dst);
      bf16_t* dstv = &Vt[bf][(c * 256 + wave * 64) * 8];
      gld_lds16(&vbase[(size_t)(idx >> 3) * T_ + kv * 64 + (idx & 7) * 8], dstv);
    }
  };
  stage(0, 0);

  for (int kv = 0; kv < nkvB; ++kv) {
    const bf16_t* ks = Ks[kv & 1];
    const bf16_t* vt = Vt[kv & 1];
    // barrier drains vmcnt -> deposits for tile kv landed (all waves), and all
    // waves finished compute(kv-1) -> buf^1 is free for the next prefetch.
    __syncthreads();
    if (kv + 1 < nkvB) stage(kv + 1, (kv + 1) & 1);

    DO_HALF(qB, oB, lB, kv == qtB, ks, vt);
    if (kv < nkvA) DO_HALF(qA, oA, lA, kv == qtA, ks, vt);
  }

  // epilogue: reduce l across quads, normalize, write ctxb [B][T][H*DH]
  lA += __shfl_xor(lA, 16, 64);
  lA += __shfl_xor(lA, 32, 64);
  lB += __shfl_xor(lB, 16, 64);
  lB += __shfl_xor(lB, 32, 64);
  float invA = 1.0f / lA, invB = 1.0f / lB;
#pragma unroll
  for (int r = 0; r < 4; ++r) {
    float iAr = __shfl(invA, quad * 4 + r, 64);
    float iBr = __shfl(invB, quad * 4 + r, 64);
    int tA = qtA * 64 + wave * 16 + quad * 4 + r;
    int tB = qtB * 64 + wave * 16 + quad * 4 + r;
#pragma unroll
    for (int dn = 0; dn < 4; ++dn) {
      ctxb[(size_t)(b * T_ + tA) * D_ + h * 64 + dn * 16 + l15] = (bf16_t)(oA[dn][r] * iAr);
      ctxb[(size_t)(b * T_ + tB) * D_ + h * 64 + dn * 16 + l15] = (bf16_t)(oB[dn][r] * iBr);
    }
  }
}

// ---------------------------------------------------------------------- launcher
extern "C" void kernel_launch(void* const* d_in, const int* in_sizes, int n_in,
                              void* d_out, int out_size, void* d_ws, size_t ws_size,
                              hipStream_t stream) {
  const float* x = (const float*)d_in[0];
  const float* Wq = (const float*)d_in[1];
  const float* Wk = (const float*)d_in[2];
  const float* Wv = (const float*)d_in[3];
  const float* Wo = (const float*)d_in[4];
  float* out = (float*)d_out;

  char* ws = (char*)d_ws;
  size_t off = 0;
  bf16_t* xb = (bf16_t*)(ws + off); off += (size_t)B_ * T_ * D_ * 2;
  bf16_t* wqkvb = (bf16_t*)(ws + off); off += (size_t)3072 * 2048 * 2;
  bf16_t* wob = (bf16_t*)(ws + off); off += (size_t)2048 * 2048 * 2;
  bf16_t* qkv = (bf16_t*)(ws + off); off += (size_t)4096 * 3072 * 2;
  bf16_t* qr = (bf16_t*)(ws + off); off += (size_t)B_ * H_ * T_ * DH_ * 2;
  bf16_t* kr = (bf16_t*)(ws + off); off += (size_t)B_ * HKV_ * T_ * DH_ * 2;
  bf16_t* vtr = (bf16_t*)(ws + off); off += (size_t)B_ * HKV_ * T_ * DH_ * 2;
  bf16_t* ctxb = (bf16_t*)(ws + off); off += (size_t)B_ * T_ * D_ * 2;

  int nx = B_ * T_ * D_;
  cast_f32_bf16<<<nx / 8 / 256, 256, 0, stream>>>(x, xb, nx);
  transpose_wqkv<<<dim3(3072 / 64, 2048 / 64), 256, 0, stream>>>(Wq, Wk, Wv, wqkvb);
  transpose_w<<<dim3(2048 / 64, 2048 / 64), 256, 0, stream>>>(Wo, wob, 2048, 2048);

  gemm_bt<bf16_t><<<dim3(3072 / 128, 4096 / 128), 256, 0, stream>>>(xb, wqkvb, qkv, 4096, 3072, 2048);

  rope_qk<<<dim3(T_, B_), 256, 0, stream>>>(qkv, qr, kr);
  transpose_v<<<dim3(T_ / 64, HKV_, B_), 256, 0, stream>>>(qkv, vtr);

  flash_attn<<<dim3(16, H_, B_), 256, 0, stream>>>(qr, kr, vtr, ctxb);

  gemm_bt<float><<<dim3(2048 / 128, 4096 / 128), 256, 0, stream>>>(ctxb, wob, out, 4096, 2048, 2048);
}